// Round 1
// baseline (373.657 us; speedup 1.0000x reference)
//
#include <hip/hip_runtime.h>

// images: [B=64, C=3, H=512, W=512] f32
// patches: [B, P=4096, C, 8, 8]; patch p = ph*64 + pw
// contrast[b][p] = (max - min + 1e-8) / (max + min) over 192 elems
// top-512 per image (ties -> lower index), zero the rest, output patch layout.
//
// v2 structure:
//   A: fused contrast + full-output zero-fill (read 192MiB || NT-write 192MiB)
//   B: per-image threshold via seeded binary search; emits compacted index list
//   C: selected-patches-only gather+write (24MiB R + 24MiB W)

#define B_IMG 64
#define NPAT 4096
#define TOPK 512

typedef float f32x4 __attribute__((ext_vector_type(4)));

// key = (contrast_bits << 12) | (4095 - p): 42 bits, unique, larger = better,
// ties broken toward LOWER patch index (matches jax top_k).
__device__ __forceinline__ unsigned long long make_key(unsigned int fb, int p) {
    return ((unsigned long long)fb << 12) | (unsigned)(NPAT - 1 - p);
}

__device__ __forceinline__ unsigned long long shfl_xor_u64(unsigned long long v, int m) {
    unsigned int lo = (unsigned int)v;
    unsigned int hi = (unsigned int)(v >> 32);
    lo = __shfl_xor(lo, m);
    hi = __shfl_xor(hi, m);
    return ((unsigned long long)hi << 32) | lo;
}

// ---------------- Kernel A: fused contrast + zero-fill ----------------
// grid 8192 blocks, role = blk&1 interleaved so reader and writer blocks
// co-schedule across all CUs (HBM read stream overlaps NT write stream).
//   role 0 (sub = blk>>1): contrast for (b, ph) as before.
//   role 1: zero a contiguous 48 KB slice of out with NT stores.
__global__ __launch_bounds__(256) void contrast_zero_kernel(const float* __restrict__ in,
                                                            float* __restrict__ contrast,
                                                            f32x4* __restrict__ out) {
    const int blk  = blockIdx.x;
    const int role = blk & 1;
    const int sub  = blk >> 1;          // 0..4095
    const int tid  = threadIdx.x;

    if (role) {
        // zero 3072 float4 = 48 KB, fully coalesced, non-temporal
        const size_t base = (size_t)sub * 3072;
        const f32x4 z = (f32x4){0.f, 0.f, 0.f, 0.f};
        #pragma unroll
        for (int it = 0; it < 12; ++it)
            __builtin_nontemporal_store(z, &out[base + (size_t)it * 256 + tid]);
        return;
    }

    const int b  = sub >> 6;
    const int ph = sub & 63;
    const int pw = tid >> 2;   // 0..63
    const int s4 = tid & 3;    // 0..3

    float mx = -1e30f, mn = 1e30f;
    #pragma unroll
    for (int i = 0; i < 6; ++i) {
        const int r  = s4 * 6 + i;       // 0..23
        const int c  = r >> 3;           // 0..2
        const int py = r & 7;            // 0..7
        const size_t base = (((size_t)b * 3 + c) * 512 + (size_t)ph * 8 + py) * 512
                          + (size_t)pw * 8;
        const float4* rp = (const float4*)(in + base);
        float4 a = rp[0];
        float4 d = rp[1];
        mx = fmaxf(mx, fmaxf(fmaxf(a.x, a.y), fmaxf(a.z, a.w)));
        mx = fmaxf(mx, fmaxf(fmaxf(d.x, d.y), fmaxf(d.z, d.w)));
        mn = fminf(mn, fminf(fminf(a.x, a.y), fminf(a.z, a.w)));
        mn = fminf(mn, fminf(fminf(d.x, d.y), fminf(d.z, d.w)));
    }
    mx = fmaxf(mx, __shfl_xor(mx, 1));
    mx = fmaxf(mx, __shfl_xor(mx, 2));
    mn = fminf(mn, __shfl_xor(mn, 1));
    mn = fminf(mn, __shfl_xor(mn, 2));

    if (s4 == 0) {
        const float ctr = (mx - mn + 1e-8f) / (mx + mn);  // IEEE f32, matches ref
        contrast[(size_t)b * NPAT + (size_t)ph * 64 + pw] = ctr;
    }
}

// ---------------- Kernel B: threshold + compacted index list ----------------
// One block per image; 16 keys/thread in registers. Binary search seeded with
// the block min/max key (values cluster -> ~30 rounds instead of 42), one
// barrier per round via double-buffered cross-wave sums. Then emit the 512
// selected patch indices (order within the list is irrelevant).
__global__ __launch_bounds__(256) void topk_kernel(const float* __restrict__ contrast,
                                                   int* __restrict__ list) {
    const int b   = blockIdx.x;
    const int tid = threadIdx.x;
    const float4* row4 = (const float4*)(contrast + (size_t)b * NPAT);

    unsigned long long k[16];
    #pragma unroll
    for (int j = 0; j < 4; ++j) {
        const float4 v = row4[tid * 4 + j];
        const int base = tid * 16 + j * 4;
        k[j * 4 + 0] = make_key(__float_as_uint(v.x), base + 0);
        k[j * 4 + 1] = make_key(__float_as_uint(v.y), base + 1);
        k[j * 4 + 2] = make_key(__float_as_uint(v.z), base + 2);
        k[j * 4 + 3] = make_key(__float_as_uint(v.w), base + 3);
    }

    // block-wide min/max seed
    unsigned long long mn = k[0], mx = k[0];
    #pragma unroll
    for (int j = 1; j < 16; ++j) {
        mn = (k[j] < mn) ? k[j] : mn;
        mx = (k[j] > mx) ? k[j] : mx;
    }
    #pragma unroll
    for (int off = 32; off > 0; off >>= 1) {
        unsigned long long on = shfl_xor_u64(mn, off);
        unsigned long long ox = shfl_xor_u64(mx, off);
        mn = (on < mn) ? on : mn;
        mx = (ox > mx) ? ox : mx;
    }
    __shared__ unsigned long long smm[8];
    if ((tid & 63) == 0) { smm[tid >> 6] = mn; smm[4 + (tid >> 6)] = mx; }
    __syncthreads();
    unsigned long long lo = smm[0];
    unsigned long long hi = smm[4];
    #pragma unroll
    for (int w = 1; w < 4; ++w) {
        lo = (smm[w] < lo) ? smm[w] : lo;
        hi = (smm[4 + w] > hi) ? smm[4 + w] : hi;
    }
    // invariant: count(>=lo) == 4096 >= 512; count(>=hi) == 1 < 512 (keys unique)

    __shared__ int wsum[2][4];
    int parity = 0;
    while (hi - lo > 1ULL) {
        const unsigned long long mid = lo + ((hi - lo) >> 1);
        int c = 0;
        #pragma unroll
        for (int j = 0; j < 16; ++j) c += (k[j] >= mid) ? 1 : 0;
        #pragma unroll
        for (int off = 32; off > 0; off >>= 1) c += __shfl_xor(c, off);
        if ((tid & 63) == 0) wsum[parity][tid >> 6] = c;
        __syncthreads();
        const int total = wsum[parity][0] + wsum[parity][1]
                        + wsum[parity][2] + wsum[parity][3];
        if (total >= TOPK) lo = mid; else hi = mid;
        parity ^= 1;   // double buffer: no second barrier needed
    }
    // keys unique => count(>= lo) == 512 exactly

    __shared__ int cnt;
    if (tid == 0) cnt = 0;
    __syncthreads();
    int* mylist = list + b * TOPK;
    #pragma unroll
    for (int j = 0; j < 16; ++j) {
        if (k[j] >= lo) {
            const int pos = atomicAdd(&cnt, 1);
            mylist[pos] = tid * 16 + j;
        }
    }
}

// ---------------- Kernel C: selected-patches-only gather/write ----------------
// grid 2048 blocks: 32 blocks per image, 16 selected patches per block.
// Per patch: 48 float4 (768 B) contiguous in output; input gather is the same
// 32 B-granular pattern as before but now only for winners (~24 MiB total,
// L3-resident after kernel A's read).
__global__ __launch_bounds__(256) void gather_kernel(const float* __restrict__ in,
                                                     const int* __restrict__ list,
                                                     f32x4* __restrict__ out) {
    const int blk   = blockIdx.x;
    const int b     = blk >> 5;
    const int chunk = blk & 31;
    const int tid   = threadIdx.x;

    __shared__ int plist[16];
    if (tid < 16) plist[tid] = list[b * TOPK + chunk * 16 + tid];
    __syncthreads();

    const f32x4* in4 = (const f32x4*)in;
    #pragma unroll
    for (int it = 0; it < 3; ++it) {
        const int idx = it * 256 + tid;    // 0..767
        const int pl  = idx / 48;          // local selected patch 0..15
        const int rem = idx - pl * 48;     // 0..47
        const int p   = plist[pl];
        const int c    = rem >> 4;         // 0..2
        const int t    = rem & 15;
        const int py   = t >> 1;           // 0..7
        const int half = t & 1;
        const int ph = p >> 6, pw = p & 63;
        const size_t a = (((size_t)b * 3 + c) * 512 + (size_t)ph * 8 + py) * 128
                       + (size_t)pw * 2 + half;
        const f32x4 v = in4[a];
        __builtin_nontemporal_store(v, &out[((size_t)b * NPAT + p) * 48 + rem]);
    }
}

extern "C" void kernel_launch(void* const* d_in, const int* in_sizes, int n_in,
                              void* d_out, int out_size, void* d_ws, size_t ws_size,
                              hipStream_t stream) {
    const float* in = (const float*)d_in[0];
    f32x4* out = (f32x4*)d_out;

    float* contrast = (float*)d_ws;                                    // 1 MB
    int* list = (int*)((char*)d_ws + (size_t)B_IMG * NPAT * sizeof(float)); // 128 KB

    contrast_zero_kernel<<<2 * B_IMG * 64, 256, 0, stream>>>(in, contrast, out);
    topk_kernel<<<B_IMG, 256, 0, stream>>>(contrast, list);
    gather_kernel<<<B_IMG * 32, 256, 0, stream>>>(in, list, out);
}

// Round 3
// 354.067 us; speedup vs baseline: 1.0553x; 1.0553x over previous
//
#include <hip/hip_runtime.h>

// images: [B=64, C=3, H=512, W=512] f32
// patches: [B, P=4096, C, 8, 8]; patch p = ph*64 + pw
// contrast[b][p] = (max - min + 1e-8) / (max + min) over 192 elems
// top-512 per image (ties -> lower index), zero the rest, output patch layout.
//
// v4 = verified v1 3-kernel phase-pure structure + verified v2 seeded topk.
//   K1: contrast (pure 201 MB read)
//   K2: per-image threshold, min/max-seeded binary search (~30 rounds, 1 barrier/round)
//   K3: single-pass zero-or-gather NT write (201 MB W + ~24 MB L3-resident R)

#define B_IMG 64
#define NPAT 4096
#define TOPK 512

typedef float f32x4 __attribute__((ext_vector_type(4)));

// key = (contrast_bits << 12) | (4095 - p): 42 bits, unique, larger = better,
// ties broken toward LOWER patch index (matches jax top_k).
__device__ __forceinline__ unsigned long long make_key(unsigned int fb, int p) {
    return ((unsigned long long)fb << 12) | (unsigned)(NPAT - 1 - p);
}

__device__ __forceinline__ unsigned long long shfl_xor_u64(unsigned long long v, int m) {
    unsigned int lo = (unsigned int)v;
    unsigned int hi = (unsigned int)(v >> 32);
    lo = __shfl_xor(lo, m);
    hi = __shfl_xor(hi, m);
    return ((unsigned long long)hi << 32) | lo;
}

// ---------------- Kernel 1: per-patch contrast (verified v1) ----------------
// grid: 4096 blocks = (b, ph); block: 256 threads; 4 threads per patch (pw).
__global__ __launch_bounds__(256) void contrast_kernel(const float* __restrict__ in,
                                                       float* __restrict__ contrast) {
    const int blk = blockIdx.x;
    const int b  = blk >> 6;
    const int ph = blk & 63;
    const int tid = threadIdx.x;
    const int pw  = tid >> 2;   // 0..63
    const int sub = tid & 3;    // 0..3

    float mx = -1e30f, mn = 1e30f;
    #pragma unroll
    for (int i = 0; i < 6; ++i) {
        const int r  = sub * 6 + i;      // 0..23
        const int c  = r >> 3;           // 0..2
        const int py = r & 7;            // 0..7
        const size_t base = (((size_t)b * 3 + c) * 512 + (size_t)ph * 8 + py) * 512
                          + (size_t)pw * 8;
        const float4* rp = (const float4*)(in + base);
        float4 a = rp[0];
        float4 d = rp[1];
        mx = fmaxf(mx, fmaxf(fmaxf(a.x, a.y), fmaxf(a.z, a.w)));
        mx = fmaxf(mx, fmaxf(fmaxf(d.x, d.y), fmaxf(d.z, d.w)));
        mn = fminf(mn, fminf(fminf(a.x, a.y), fminf(a.z, a.w)));
        mn = fminf(mn, fminf(fminf(d.x, d.y), fminf(d.z, d.w)));
    }
    mx = fmaxf(mx, __shfl_xor(mx, 1));
    mx = fmaxf(mx, __shfl_xor(mx, 2));
    mn = fminf(mn, __shfl_xor(mn, 1));
    mn = fminf(mn, __shfl_xor(mn, 2));

    if (sub == 0) {
        const float ctr = (mx - mn + 1e-8f) / (mx + mn);  // IEEE f32, matches ref
        contrast[(size_t)b * NPAT + (size_t)ph * 64 + pw] = ctr;
    }
}

// ---------------- Kernel 2: seeded binary-search threshold (verified v2) ----
// One block per image; 16 keys/thread in registers. Search seeded with block
// min/max (values cluster -> ~30 rounds), one barrier per round via
// double-buffered cross-wave sums. Keys unique => exact count==512 at lo.
__global__ __launch_bounds__(256) void topk_kernel(const float* __restrict__ contrast,
                                                   unsigned long long* __restrict__ thresh) {
    const int b   = blockIdx.x;
    const int tid = threadIdx.x;
    const float4* row4 = (const float4*)(contrast + (size_t)b * NPAT);

    unsigned long long k[16];
    #pragma unroll
    for (int j = 0; j < 4; ++j) {
        const float4 v = row4[tid * 4 + j];
        const int base = tid * 16 + j * 4;
        k[j * 4 + 0] = make_key(__float_as_uint(v.x), base + 0);
        k[j * 4 + 1] = make_key(__float_as_uint(v.y), base + 1);
        k[j * 4 + 2] = make_key(__float_as_uint(v.z), base + 2);
        k[j * 4 + 3] = make_key(__float_as_uint(v.w), base + 3);
    }

    // block-wide min/max seed
    unsigned long long mn = k[0], mx = k[0];
    #pragma unroll
    for (int j = 1; j < 16; ++j) {
        mn = (k[j] < mn) ? k[j] : mn;
        mx = (k[j] > mx) ? k[j] : mx;
    }
    #pragma unroll
    for (int off = 32; off > 0; off >>= 1) {
        unsigned long long on = shfl_xor_u64(mn, off);
        unsigned long long ox = shfl_xor_u64(mx, off);
        mn = (on < mn) ? on : mn;
        mx = (ox > mx) ? ox : mx;
    }
    __shared__ unsigned long long smm[8];
    if ((tid & 63) == 0) { smm[tid >> 6] = mn; smm[4 + (tid >> 6)] = mx; }
    __syncthreads();
    unsigned long long lo = smm[0];
    unsigned long long hi = smm[4];
    #pragma unroll
    for (int w = 1; w < 4; ++w) {
        lo = (smm[w] < lo) ? smm[w] : lo;
        hi = (smm[4 + w] > hi) ? smm[4 + w] : hi;
    }
    // invariant: count(>=lo) == 4096 >= 512; count(>=hi) == 1 < 512 (keys unique)

    __shared__ int wsum[2][4];
    int parity = 0;
    while (hi - lo > 1ULL) {
        const unsigned long long mid = lo + ((hi - lo) >> 1);
        int c = 0;
        #pragma unroll
        for (int j = 0; j < 16; ++j) c += (k[j] >= mid) ? 1 : 0;
        #pragma unroll
        for (int off = 32; off > 0; off >>= 1) c += __shfl_xor(c, off);
        if ((tid & 63) == 0) wsum[parity][tid >> 6] = c;
        __syncthreads();
        const int total = wsum[parity][0] + wsum[parity][1]
                        + wsum[parity][2] + wsum[parity][3];
        if (total >= TOPK) lo = mid; else hi = mid;
        parity ^= 1;   // double buffer: no second barrier needed
    }
    // termination: hi == lo+1, count(>=lo) >= 512 > count(>=lo+1)
    // unique keys => count(>=lo) == 512 exactly
    if (tid == 0) thresh[b] = lo;
}

// ---------------- Kernel 3: masked gather/write (verified v1) ----------------
// grid: 4096 blocks = (b, ph); block: 256 threads.
// Output region for a block: 64 patches * 192 floats = 3072 float4, contiguous.
// NT stores: output never re-read; keeps the input L3-resident for the gather.
__global__ __launch_bounds__(256) void write_kernel(const float* __restrict__ in,
                                                    const float* __restrict__ contrast,
                                                    const unsigned long long* __restrict__ thresh,
                                                    f32x4* __restrict__ out) {
    const int blk = blockIdx.x;
    const int b  = blk >> 6;
    const int ph = blk & 63;

    __shared__ int sel[64];
    if (threadIdx.x < 64) {
        const int p = ph * 64 + threadIdx.x;
        const unsigned int fb = __float_as_uint(contrast[(size_t)b * NPAT + p]);
        sel[threadIdx.x] = (make_key(fb, p) >= thresh[b]) ? 1 : 0;
    }
    __syncthreads();

    const f32x4* in4 = (const f32x4*)in;
    const size_t out_base = ((size_t)b * NPAT + (size_t)ph * 64) * 48;  // float4 units

    #pragma unroll
    for (int it = 0; it < 12; ++it) {
        const int idx = it * 256 + threadIdx.x;   // 0..3071
        const int pl  = idx / 48;                 // local patch 0..63
        const int rem = idx - pl * 48;            // 0..47
        f32x4 v = (f32x4){0.f, 0.f, 0.f, 0.f};
        if (sel[pl]) {
            const int c    = rem >> 4;            // 0..2
            const int t    = rem & 15;
            const int py   = t >> 1;              // 0..7
            const int half = t & 1;               // 0..1
            const size_t a = (((size_t)b * 3 + c) * 512 + (size_t)ph * 8 + py) * 128
                           + (size_t)pl * 2 + half;
            v = in4[a];
        }
        __builtin_nontemporal_store(v, &out[out_base + idx]);  // coalesced, nt
    }
}

extern "C" void kernel_launch(void* const* d_in, const int* in_sizes, int n_in,
                              void* d_out, int out_size, void* d_ws, size_t ws_size,
                              hipStream_t stream) {
    const float* in = (const float*)d_in[0];
    float* out = (float*)d_out;

    float* contrast = (float*)d_ws;                                   // 1 MB
    unsigned long long* thresh =
        (unsigned long long*)((char*)d_ws + (size_t)B_IMG * NPAT * sizeof(float));

    contrast_kernel<<<B_IMG * 64, 256, 0, stream>>>(in, contrast);
    topk_kernel<<<B_IMG, 256, 0, stream>>>(contrast, thresh);
    write_kernel<<<B_IMG * 64, 256, 0, stream>>>(in, contrast, thresh, (f32x4*)out);
}